// Round 1
// baseline (2485.043 us; speedup 1.0000x reference)
//
#include <hip/hip_runtime.h>

typedef unsigned short u16;
typedef short bf16x8 __attribute__((ext_vector_type(8)));
typedef float f32x4 __attribute__((ext_vector_type(4)));
typedef u16 u16x4 __attribute__((ext_vector_type(4)));

#define TT     1024
#define EE     768
#define NHH    12
#define ND     2048
#define VOC    32000
#define HNN    24576
#define NLAYER 6          // setup_inputs() fixes n_layer=6 (device scalar, unreadable host-side)
#define LN_EPS 1e-5f

// ---------- bf16 helpers (manual RNE, no hip_bf16 dependency) ----------
__device__ __forceinline__ float b2f(u16 u){
  unsigned int x = ((unsigned int)u) << 16; float f; __builtin_memcpy(&f, &x, 4); return f;
}
__device__ __forceinline__ u16 f2b(float f){
  unsigned int x; __builtin_memcpy(&x, &f, 4);
  x = x + 0x7fffu + ((x >> 16) & 1u);
  return (u16)(x >> 16);
}

// ---------- async global->LDS, 16B per lane (m97 pattern) ----------
__device__ __forceinline__ void gload16(const void* g, void* lds){
  __builtin_amdgcn_global_load_lds(
      (const __attribute__((address_space(1))) unsigned int*)g,
      (__attribute__((address_space(3))) unsigned int*)(unsigned int)(unsigned long long)lds,
      16, 0, 0);
}

// ---------- block reductions (256 threads = 4 waves) ----------
__device__ __forceinline__ void blk_sum2(float& a, float& b){
  #pragma unroll
  for (int o = 32; o > 0; o >>= 1){ a += __shfl_down(a, o); b += __shfl_down(b, o); }
  __shared__ float sa[4], sb[4];
  int lane = threadIdx.x & 63, wid = threadIdx.x >> 6;
  __syncthreads();                       // guard shared reuse across calls
  if (lane == 0){ sa[wid] = a; sb[wid] = b; }
  __syncthreads();
  a = (sa[0] + sa[1]) + (sa[2] + sa[3]);
  b = (sb[0] + sb[1]) + (sb[2] + sb[3]);
}
__device__ __forceinline__ float blk_max(float v){
  #pragma unroll
  for (int o = 32; o > 0; o >>= 1) v = fmaxf(v, __shfl_down(v, o));
  __shared__ float sm[4];
  int lane = threadIdx.x & 63, wid = threadIdx.x >> 6;
  __syncthreads();
  if (lane == 0) sm[wid] = v;
  __syncthreads();
  return fmaxf(fmaxf(sm[0], sm[1]), fmaxf(sm[2], sm[3]));
}
__device__ __forceinline__ float blk_sum(float v){
  #pragma unroll
  for (int o = 32; o > 0; o >>= 1) v += __shfl_down(v, o);
  __shared__ float ss[4];
  int lane = threadIdx.x & 63, wid = threadIdx.x >> 6;
  __syncthreads();
  if (lane == 0) ss[wid] = v;
  __syncthreads();
  return (ss[0] + ss[1]) + (ss[2] + ss[3]);
}

// ---------- weight preprocessing ----------
// in: z-th f32 matrix [R][Cc]; out: z-th bf16 matrix [Cc][R]
__global__ void transpose_f2b(const float* __restrict__ in, long sIn,
                              u16* __restrict__ out, long sOut, int R, int Cc){
  __shared__ float tile[32][33];
  int z = blockIdx.z;
  in  += (long)z * sIn;
  out += (long)z * sOut;
  int c0 = blockIdx.x * 32, r0 = blockIdx.y * 32;
  int lx = threadIdx.x & 31, ly = threadIdx.x >> 5;   // 32 x 8
  #pragma unroll
  for (int i = 0; i < 32; i += 8)
    tile[ly + i][lx] = in[(long)(r0 + ly + i) * Cc + (c0 + lx)];
  __syncthreads();
  #pragma unroll
  for (int i = 0; i < 32; i += 8)
    out[(long)(c0 + ly + i) * R + (r0 + lx)] = f2b(tile[lx][ly + i]);
}

__global__ void conv_f2b(const float* __restrict__ in, u16* __restrict__ out){
  long i = ((long)blockIdx.x * 256 + threadIdx.x) * 4;
  float4 v = *(const float4*)(in + i);
  u16x4 o; o.x = f2b(v.x); o.y = f2b(v.y); o.z = f2b(v.z); o.w = f2b(v.w);
  *(u16x4*)(out + i) = o;
}

// ---------- embed gather + LN ----------
__global__ void embed_ln(const int* __restrict__ idx, const float* __restrict__ emb,
                         const float* __restrict__ w, const float* __restrict__ b,
                         float* __restrict__ xf, u16* __restrict__ xb, u16* __restrict__ xT){
  int t = blockIdx.x, tid = threadIdx.x;
  const float* src = emb + (long)idx[t] * EE;
  float v[3];
  #pragma unroll
  for (int j = 0; j < 3; j++) v[j] = src[tid + j * 256];
  float s = v[0] + v[1] + v[2];
  float s2 = v[0]*v[0] + v[1]*v[1] + v[2]*v[2];
  blk_sum2(s, s2);
  float m  = s * (1.0f / EE);
  float var = s2 * (1.0f / EE) - m * m;
  float rs = rsqrtf(var + LN_EPS);
  #pragma unroll
  for (int j = 0; j < 3; j++){
    int e = tid + j * 256;
    float o = (v[j] - m) * rs * w[e] + b[e];
    xf[(long)t * EE + e] = o;
    u16 ob = f2b(o);
    xb[(long)t * EE + e] = ob;
    xT[(long)e * TT + t] = ob;
  }
}

// ---------- generic row LN (E=768), f32 in -> bf16 out ----------
__global__ void ln_rows(const float* __restrict__ in, u16* __restrict__ out,
                        const float* __restrict__ w, const float* __restrict__ b){
  long row = blockIdx.x; int tid = threadIdx.x;
  const float* src = in + row * EE;
  float v[3];
  #pragma unroll
  for (int j = 0; j < 3; j++) v[j] = src[tid + j * 256];
  float s = v[0] + v[1] + v[2];
  float s2 = v[0]*v[0] + v[1]*v[1] + v[2]*v[2];
  blk_sum2(s, s2);
  float m = s * (1.0f / EE);
  float var = s2 * (1.0f / EE) - m * m;
  float rs = rsqrtf(var + LN_EPS);
  #pragma unroll
  for (int j = 0; j < 3; j++){
    int e = tid + j * 256;
    out[row * EE + e] = f2b((v[j] - m) * rs * w[e] + b[e]);
  }
}

// ---------- softmax over a 1024 row (masked entries hold -1e30) ----------
__global__ void softmax_rows(const float* __restrict__ scores, u16* __restrict__ attn){
  int q = blockIdx.x, h = blockIdx.y, tid = threadIdx.x;
  const float* srow = scores + ((long)h * TT + q) * TT;
  u16* arow = attn + ((long)h * TT + q) * TT;
  float4 v = *(const float4*)(srow + tid * 4);
  float mx = blk_max(fmaxf(fmaxf(v.x, v.y), fmaxf(v.z, v.w)));
  float e0 = __expf(v.x - mx), e1 = __expf(v.y - mx);
  float e2 = __expf(v.z - mx), e3 = __expf(v.w - mx);
  float inv = 1.0f / blk_sum(e0 + e1 + e2 + e3);
  u16x4 o; o.x = f2b(e0 * inv); o.y = f2b(e1 * inv); o.z = f2b(e2 * inv); o.w = f2b(e3 * inv);
  *(u16x4*)(arow + tid * 4) = o;
}

// ---------- residual: x = ln(x + ln(sum_p part_p)) ; also emit bf16 + bf16^T ----------
__global__ void residual_ln(const float* __restrict__ part, const float* __restrict__ xin,
                            float* __restrict__ xf, u16* __restrict__ xb, u16* __restrict__ xT,
                            const float* __restrict__ w, const float* __restrict__ b){
  int t = blockIdx.x, tid = threadIdx.x;
  float g[3];
  #pragma unroll
  for (int j = 0; j < 3; j++){
    int e = tid + j * 256;
    float s = 0.f;
    #pragma unroll
    for (int pp = 0; pp < 8; pp++) s += part[((long)pp * TT + t) * EE + e];
    g[j] = s;
  }
  float s = g[0] + g[1] + g[2], s2 = g[0]*g[0] + g[1]*g[1] + g[2]*g[2];
  blk_sum2(s, s2);
  float m = s * (1.0f / EE), var = s2 * (1.0f / EE) - m * m;
  float rs = rsqrtf(var + LN_EPS);
  float hh[3];
  #pragma unroll
  for (int j = 0; j < 3; j++){
    int e = tid + j * 256;
    hh[j] = xin[(long)t * EE + e] + ((g[j] - m) * rs * w[e] + b[e]);
  }
  s = hh[0] + hh[1] + hh[2]; s2 = hh[0]*hh[0] + hh[1]*hh[1] + hh[2]*hh[2];
  blk_sum2(s, s2);
  m = s * (1.0f / EE); var = s2 * (1.0f / EE) - m * m; rs = rsqrtf(var + LN_EPS);
  #pragma unroll
  for (int j = 0; j < 3; j++){
    int e = tid + j * 256;
    float o = (hh[j] - m) * rs * w[e] + b[e];
    xf[(long)t * EE + e] = o;
    u16 ob = f2b(o);
    xb[(long)t * EE + e] = ob;
    xT[(long)e * TT + t] = ob;
  }
}

// ---------- NT GEMM: C[m][n] = epi( sum_k A[m][k] * B[n][k] ), 128x128x32, 4 waves ----------
// EPI: 0 = f32 store | 1 = relu -> bf16 | 2 = *scale, causal mask (col>row -> -1e30), f32
//      3 = relu * Mul[row][col] -> bf16 (xy fusion; sC is a COLUMN offset into ldc-wide C)
#define BM 128
#define BN 128
#define BK 32

template<int EPI>
__global__ __launch_bounds__(256)
void gemm_nt(const u16* __restrict__ Ab, long sA,
             const u16* __restrict__ Bb, long sB,
             void* __restrict__ Cb, long sC,
             int M, int Nn, int K, int lda, int ldb, int ldc,
             float scale,
             const u16* __restrict__ Mul, long sMul, int ldmul){
  __shared__ u16 As[BM * BK];
  __shared__ u16 Bs[BN * BK];
  const int z = blockIdx.z;
  const u16* A = Ab + (long)z * sA;
  const u16* B = Bb + (long)z * sB;
  const int m0 = blockIdx.x * BM, n0 = blockIdx.y * BN;
  const int tid = threadIdx.x, lane = tid & 63, wid = tid >> 6;

  if (EPI == 2 && n0 > m0 + (BM - 1)){          // fully-masked causal block
    float* C = (float*)Cb + (long)z * sC;
    #pragma unroll
    for (int i = 0; i < 16; i++){
      int idx4 = (tid + i * 256) * 4;           // 0..16380
      int r = idx4 >> 7, c = idx4 & 127;
      *(float4*)&C[(long)(m0 + r) * ldc + n0 + c] = make_float4(-1e30f, -1e30f, -1e30f, -1e30f);
    }
    return;
  }

  f32x4 acc[4][4] = {};
  const int wr = wid >> 1, wc = wid & 1;        // 2x2 waves, each 64x64
  const int fr = lane & 15, fk = lane >> 4;

  for (int k0 = 0; k0 < K; k0 += BK){
    {   // stage A,B tiles: per wave 2+2 issues of 16 rows x 64B
      const u16* ga = A + (long)(m0 + wid * 32 + (lane >> 2)) * lda + k0 + (lane & 3) * 8;
      gload16(ga,            (void*)&As[(wid * 32) * BK]);
      gload16(ga + 16 * lda, (void*)&As[(wid * 32 + 16) * BK]);
      const u16* gb = B + (long)(n0 + wid * 32 + (lane >> 2)) * ldb + k0 + (lane & 3) * 8;
      gload16(gb,            (void*)&Bs[(wid * 32) * BK]);
      gload16(gb + 16 * ldb, (void*)&Bs[(wid * 32 + 16) * BK]);
    }
    asm volatile("s_waitcnt vmcnt(0)" ::: "memory");
    __syncthreads();
    bf16x8 af[4], bfv[4];
    #pragma unroll
    for (int mi = 0; mi < 4; mi++)
      af[mi] = *(const bf16x8*)&As[(wr * 64 + mi * 16 + fr) * BK + fk * 8];
    #pragma unroll
    for (int ni = 0; ni < 4; ni++)
      bfv[ni] = *(const bf16x8*)&Bs[(wc * 64 + ni * 16 + fr) * BK + fk * 8];
    #pragma unroll
    for (int mi = 0; mi < 4; mi++)
      #pragma unroll
      for (int ni = 0; ni < 4; ni++)
        acc[mi][ni] = __builtin_amdgcn_mfma_f32_16x16x32_bf16(af[mi], bfv[ni], acc[mi][ni], 0, 0, 0);
    __syncthreads();
  }

  // epilogue: D col = lane&15, row = (lane>>4)*4 + j  [verified m89/m91]
  const int er = (lane >> 4) * 4, ec = lane & 15;
  #pragma unroll
  for (int mi = 0; mi < 4; mi++){
    #pragma unroll
    for (int ni = 0; ni < 4; ni++){
      #pragma unroll
      for (int j = 0; j < 4; j++){
        int row = m0 + wr * 64 + mi * 16 + er + j;
        int col = n0 + wc * 64 + ni * 16 + ec;
        float v = acc[mi][ni][j];
        if (EPI == 0){
          ((float*)Cb + (long)z * sC)[(long)row * ldc + col] = v;
        } else if (EPI == 1){
          v = v > 0.f ? v : 0.f;
          ((u16*)Cb + (long)z * sC)[(long)row * ldc + col] = f2b(v);
        } else if (EPI == 2){
          v *= scale;
          if (col > row) v = -1e30f;
          ((float*)Cb + (long)z * sC)[(long)row * ldc + col] = v;
        } else {
          v = v > 0.f ? v : 0.f;
          float mfv = b2f((Mul + (long)z * sMul)[(long)row * ldmul + col]);
          ((u16*)Cb + (long)z * sC)[(long)row * ldc + col] = f2b(v * mfv);
        }
      }
    }
  }
}

// ---------- host ----------
extern "C" void kernel_launch(void* const* d_in, const int* in_sizes, int n_in,
                              void* d_out, int out_size, void* d_ws, size_t ws_size,
                              hipStream_t stream){
  (void)in_sizes; (void)n_in; (void)out_size; (void)ws_size;
  const int*   idx     = (const int*)  d_in[0];
  const float* embed   = (const float*)d_in[1];
  const float* encoder = (const float*)d_in[2];
  const float* encv    = (const float*)d_in[3];
  const float* decoder = (const float*)d_in[4];
  const float* lm_head = (const float*)d_in[5];
  const float* ln_w    = (const float*)d_in[6];
  const float* ln_b    = (const float*)d_in[7];
  float* out = (float*)d_out;

  // workspace carve-up (~323 MiB). scores(f32)/yf(f32)/xy(bf16) are time-disjoint -> shared region.
  char* p = (char*)d_ws;
  auto take = [&](size_t n){ char* r = p; p += (n + 255) & ~(size_t)255; return r; };
  u16*   encT  = (u16*)  take((size_t)NHH * ND * EE * 2);
  u16*   encvT = (u16*)  take((size_t)NHH * ND * EE * 2);
  u16*   decT  = (u16*)  take((size_t)EE * HNN * 2);
  u16*   lmhB  = (u16*)  take((size_t)VOC * EE * 2);
  float* xf    = (float*)take((size_t)TT * EE * 4);
  u16*   xb    = (u16*)  take((size_t)TT * EE * 2);
  u16*   xT    = (u16*)  take((size_t)EE * TT * 2);
  u16*   xs    = (u16*)  take((size_t)NHH * TT * ND * 2);
  char*  big   =         take((size_t)NHH * TT * TT * 4);
  u16*   attn  = (u16*)  take((size_t)NHH * TT * TT * 2);
  u16*   yb    = (u16*)  take((size_t)NHH * TT * EE * 2);
  float* part  = (float*)take((size_t)8 * TT * EE * 4);
  float* scores = (float*)big;
  float* yf     = (float*)big;
  u16*   xy     = (u16*)big;

  dim3 blk(256, 1, 1);

  // weights -> bf16 (transposed to NT layout)
  transpose_f2b<<<dim3(ND / 32, EE / 32, NHH), blk, 0, stream>>>(encoder, (long)EE * ND, encT,  (long)ND * EE, EE, ND);
  transpose_f2b<<<dim3(ND / 32, EE / 32, NHH), blk, 0, stream>>>(encv,    (long)EE * ND, encvT, (long)ND * EE, EE, ND);
  transpose_f2b<<<dim3(EE / 32, HNN / 32, 1),  blk, 0, stream>>>(decoder, 0, decT, 0, HNN, EE);
  conv_f2b<<<dim3((VOC * EE) / 1024, 1, 1), blk, 0, stream>>>(lm_head, lmhB);

  embed_ln<<<dim3(TT, 1, 1), blk, 0, stream>>>(idx, embed, ln_w, ln_b, xf, xb, xT);

  const float scl = 0.022097086912079608f;  // 1/sqrt(2048)

  for (int L = 0; L < NLAYER; ++L){
    // x_sparse[h] = relu(x @ enc[h])            [T,E]x[N,E]^T -> bf16 [H][T][N]
    gemm_nt<1><<<dim3(TT / 128, ND / 128, NHH), blk, 0, stream>>>(
        xb, 0, encT, (long)ND * EE, xs, (long)TT * ND,
        TT, ND, EE, EE, EE, ND, 0.f, (const u16*)0, 0, 0);
    // scores[h] = causal(scale * xs[h] @ xs[h]^T)  -> f32 [H][T][T]
    gemm_nt<2><<<dim3(TT / 128, TT / 128, NHH), blk, 0, stream>>>(
        xs, (long)TT * ND, xs, (long)TT * ND, scores, (long)TT * TT,
        TT, TT, ND, ND, ND, TT, scl, (const u16*)0, 0, 0);
    softmax_rows<<<dim3(TT, NHH, 1), blk, 0, stream>>>(scores, attn);
    // y[h] = attn[h] @ x                        [T,T]x[E,T]^T -> f32 [H][T][E]
    gemm_nt<0><<<dim3(TT / 128, EE / 128, NHH), blk, 0, stream>>>(
        attn, (long)TT * TT, xT, 0, yf, (long)TT * EE,
        TT, EE, TT, TT, TT, EE, 0.f, (const u16*)0, 0, 0);
    ln_rows<<<dim3(NHH * TT, 1, 1), blk, 0, stream>>>(yf, yb, ln_w, ln_b);
    // xy[t][h*N+n] = relu(y[h] @ encv[h]) * xs[h]  -> bf16 [T][H*N]
    gemm_nt<3><<<dim3(TT / 128, ND / 128, NHH), blk, 0, stream>>>(
        yb, (long)TT * EE, encvT, (long)ND * EE, xy, (long)ND,
        TT, ND, EE, EE, EE, HNN, 0.f, xs, (long)TT * ND, ND);
    // y_mlp partials: split-K over 24576 (8 chunks of 3072)
    gemm_nt<0><<<dim3(TT / 128, EE / 128, 8), blk, 0, stream>>>(
        xy, (long)3072, decT, (long)3072, part, (long)TT * EE,
        TT, EE, 3072, HNN, HNN, EE, 0.f, (const u16*)0, 0, 0);
    residual_ln<<<dim3(TT, 1, 1), blk, 0, stream>>>(part, xf, xf, xb, xT, ln_w, ln_b);
  }

  // logits = x @ lm_head^T  -> f32 [T][V]
  gemm_nt<0><<<dim3(TT / 128, VOC / 128, 1), blk, 0, stream>>>(
      xb, 0, lmhB, 0, out, 0,
      TT, VOC, EE, EE, EE, VOC, 0.f, (const u16*)0, 0, 0);
}

// Round 2
// 2068.619 us; speedup vs baseline: 1.2013x; 1.2013x over previous
//
#include <hip/hip_runtime.h>

typedef unsigned short u16;
typedef short bf16x8 __attribute__((ext_vector_type(8)));
typedef float f32x4 __attribute__((ext_vector_type(4)));
typedef u16 u16x4 __attribute__((ext_vector_type(4)));

#define TT     1024
#define EE     768
#define NHH    12
#define ND     2048
#define VOC    32000
#define HNN    24576
#define NLAYER 6          // setup_inputs() fixes n_layer=6 (device scalar, unreadable host-side)
#define LN_EPS 1e-5f

// ---------- bf16 helpers ----------
__device__ __forceinline__ float b2f(u16 u){
  unsigned int x = ((unsigned int)u) << 16; float f; __builtin_memcpy(&f, &x, 4); return f;
}
__device__ __forceinline__ u16 f2b(float f){
  unsigned int x; __builtin_memcpy(&x, &f, 4);
  x = x + 0x7fffu + ((x >> 16) & 1u);
  return (u16)(x >> 16);
}

// ---------- async global->LDS, 16B per lane ----------
__device__ __forceinline__ void gload16(const void* g, void* lds){
  __builtin_amdgcn_global_load_lds(
      (const __attribute__((address_space(1))) unsigned int*)g,
      (__attribute__((address_space(3))) unsigned int*)(unsigned int)(unsigned long long)lds,
      16, 0, 0);
}

// ---------- block reductions (256 threads = 4 waves) ----------
__device__ __forceinline__ void blk_sum2(float& a, float& b){
  #pragma unroll
  for (int o = 32; o > 0; o >>= 1){ a += __shfl_down(a, o); b += __shfl_down(b, o); }
  __shared__ float sa[4], sb[4];
  int lane = threadIdx.x & 63, wid = threadIdx.x >> 6;
  __syncthreads();
  if (lane == 0){ sa[wid] = a; sb[wid] = b; }
  __syncthreads();
  a = (sa[0] + sa[1]) + (sa[2] + sa[3]);
  b = (sb[0] + sb[1]) + (sb[2] + sb[3]);
}
__device__ __forceinline__ float blk_max(float v){
  #pragma unroll
  for (int o = 32; o > 0; o >>= 1) v = fmaxf(v, __shfl_down(v, o));
  __shared__ float sm[4];
  int lane = threadIdx.x & 63, wid = threadIdx.x >> 6;
  __syncthreads();
  if (lane == 0) sm[wid] = v;
  __syncthreads();
  return fmaxf(fmaxf(sm[0], sm[1]), fmaxf(sm[2], sm[3]));
}
__device__ __forceinline__ float blk_sum(float v){
  #pragma unroll
  for (int o = 32; o > 0; o >>= 1) v += __shfl_down(v, o);
  __shared__ float ss[4];
  int lane = threadIdx.x & 63, wid = threadIdx.x >> 6;
  __syncthreads();
  if (lane == 0) ss[wid] = v;
  __syncthreads();
  return (ss[0] + ss[1]) + (ss[2] + ss[3]);
}

// ---------- weight preprocessing ----------
__global__ void transpose_f2b(const float* __restrict__ in, long sIn,
                              u16* __restrict__ out, long sOut, int R, int Cc){
  __shared__ float tile[32][33];
  int z = blockIdx.z;
  in  += (long)z * sIn;
  out += (long)z * sOut;
  int c0 = blockIdx.x * 32, r0 = blockIdx.y * 32;
  int lx = threadIdx.x & 31, ly = threadIdx.x >> 5;   // 32 x 8
  #pragma unroll
  for (int i = 0; i < 32; i += 8)
    tile[ly + i][lx] = in[(long)(r0 + ly + i) * Cc + (c0 + lx)];
  __syncthreads();
  #pragma unroll
  for (int i = 0; i < 32; i += 8)
    out[(long)(c0 + ly + i) * R + (r0 + lx)] = f2b(tile[lx][ly + i]);
}

__global__ void conv_f2b(const float* __restrict__ in, u16* __restrict__ out){
  long i = ((long)blockIdx.x * 256 + threadIdx.x) * 4;
  float4 v = *(const float4*)(in + i);
  u16x4 o; o.x = f2b(v.x); o.y = f2b(v.y); o.z = f2b(v.z); o.w = f2b(v.w);
  *(u16x4*)(out + i) = o;
}

// ---------- embed gather + LN ----------
__global__ void embed_ln(const int* __restrict__ idx, const float* __restrict__ emb,
                         const float* __restrict__ w, const float* __restrict__ b,
                         float* __restrict__ xf, u16* __restrict__ xb, u16* __restrict__ xT){
  int t = blockIdx.x, tid = threadIdx.x;
  const float* src = emb + (long)idx[t] * EE;
  float v[3];
  #pragma unroll
  for (int j = 0; j < 3; j++) v[j] = src[tid + j * 256];
  float s = v[0] + v[1] + v[2];
  float s2 = v[0]*v[0] + v[1]*v[1] + v[2]*v[2];
  blk_sum2(s, s2);
  float m  = s * (1.0f / EE);
  float var = s2 * (1.0f / EE) - m * m;
  float rs = rsqrtf(var + LN_EPS);
  #pragma unroll
  for (int j = 0; j < 3; j++){
    int e = tid + j * 256;
    float o = (v[j] - m) * rs * w[e] + b[e];
    xf[(long)t * EE + e] = o;
    u16 ob = f2b(o);
    xb[(long)t * EE + e] = ob;
    xT[(long)e * TT + t] = ob;
  }
}

// ---------- generic row LN (E=768), f32 in -> bf16 out ----------
__global__ void ln_rows(const float* __restrict__ in, u16* __restrict__ out,
                        const float* __restrict__ w, const float* __restrict__ b){
  long row = blockIdx.x; int tid = threadIdx.x;
  const float* src = in + row * EE;
  float v[3];
  #pragma unroll
  for (int j = 0; j < 3; j++) v[j] = src[tid + j * 256];
  float s = v[0] + v[1] + v[2];
  float s2 = v[0]*v[0] + v[1]*v[1] + v[2]*v[2];
  blk_sum2(s, s2);
  float m = s * (1.0f / EE);
  float var = s2 * (1.0f / EE) - m * m;
  float rs = rsqrtf(var + LN_EPS);
  #pragma unroll
  for (int j = 0; j < 3; j++){
    int e = tid + j * 256;
    out[row * EE + e] = f2b((v[j] - m) * rs * w[e] + b[e]);
  }
}

// ---------- softmax over a 1024 row (masked entries hold -1e30) ----------
__global__ void softmax_rows(const float* __restrict__ scores, u16* __restrict__ attn){
  int q = blockIdx.x, h = blockIdx.y, tid = threadIdx.x;
  const float* srow = scores + ((long)h * TT + q) * TT;
  u16* arow = attn + ((long)h * TT + q) * TT;
  float4 v = *(const float4*)(srow + tid * 4);
  float mx = blk_max(fmaxf(fmaxf(v.x, v.y), fmaxf(v.z, v.w)));
  float e0 = __expf(v.x - mx), e1 = __expf(v.y - mx);
  float e2 = __expf(v.z - mx), e3 = __expf(v.w - mx);
  float inv = 1.0f / blk_sum(e0 + e1 + e2 + e3);
  u16x4 o; o.x = f2b(e0 * inv); o.y = f2b(e1 * inv); o.z = f2b(e2 * inv); o.w = f2b(e3 * inv);
  *(u16x4*)(arow + tid * 4) = o;
}

// ---------- residual: x = ln(x + ln(sum_p part_p)) ----------
__global__ void residual_ln(const float* __restrict__ part, const float* __restrict__ xin,
                            float* __restrict__ xf, u16* __restrict__ xb, u16* __restrict__ xT,
                            const float* __restrict__ w, const float* __restrict__ b){
  int t = blockIdx.x, tid = threadIdx.x;
  float g[3];
  #pragma unroll
  for (int j = 0; j < 3; j++){
    int e = tid + j * 256;
    float s = 0.f;
    #pragma unroll
    for (int pp = 0; pp < 8; pp++) s += part[((long)pp * TT + t) * EE + e];
    g[j] = s;
  }
  float s = g[0] + g[1] + g[2], s2 = g[0]*g[0] + g[1]*g[1] + g[2]*g[2];
  blk_sum2(s, s2);
  float m = s * (1.0f / EE), var = s2 * (1.0f / EE) - m * m;
  float rs = rsqrtf(var + LN_EPS);
  float hh[3];
  #pragma unroll
  for (int j = 0; j < 3; j++){
    int e = tid + j * 256;
    hh[j] = xin[(long)t * EE + e] + ((g[j] - m) * rs * w[e] + b[e]);
  }
  s = hh[0] + hh[1] + hh[2]; s2 = hh[0]*hh[0] + hh[1]*hh[1] + hh[2]*hh[2];
  blk_sum2(s, s2);
  m = s * (1.0f / EE); var = s2 * (1.0f / EE) - m * m; rs = rsqrtf(var + LN_EPS);
  #pragma unroll
  for (int j = 0; j < 3; j++){
    int e = tid + j * 256;
    float o = (hh[j] - m) * rs * w[e] + b[e];
    xf[(long)t * EE + e] = o;
    u16 ob = f2b(o);
    xb[(long)t * EE + e] = ob;
    xT[(long)e * TT + t] = ob;
  }
}

// ==========================================================================
// Pipelined NT GEMM: C[m][n] = epi( sum_k A[m][k]*B[n][k] )
// BK=32, 4 LDS buffers, prefetch depth 3, counted vmcnt(8) + raw s_barrier
// per K-tile (never drain to 0 in-loop). T2 slot-swizzle (slot ^= (row>>1)&3)
// with inverse-swizzled global source (global_load_lds dest stays linear).
// EPI: 0=f32 | 1=relu->bf16 | 2=*scale+causal(-1e30), f32 | 3=relu*Mul->bf16
// ==========================================================================
#define BK 32

template<int BM, int BN, int WM, int WN, int EPI>
__global__ __launch_bounds__(WM*WN*64, 2)
void gemm_pipe(const u16* __restrict__ Ab, long sA,
               const u16* __restrict__ Bb, long sB,
               void* __restrict__ Cb, long sC,
               int grid_m, int grid_mn,
               int K, int lda, int ldb, int ldc, float scale,
               const u16* __restrict__ Mul, long sMul, int ldmul){
  constexpr int THREADS = WM*WN*64;
  constexpr int WMR = BM/WM, WNR = BN/WN;
  constexpr int MI = WMR/16, NI = WNR/16;
  constexpr int BUF = (BM+BN)*32;                 // u16 per buffer (A then B)
  constexpr int AIT = (BM*4)/THREADS, BIT = (BN*4)/THREADS;
  __shared__ __align__(16) u16 S[4*BUF];

  // bijective XCD swizzle (m204)
  const int nwg = gridDim.x;
  const int orig = blockIdx.x;
  const int q = nwg >> 3, r = nwg & 7;
  const int xcd = orig & 7;
  const int wgid = (xcd < r ? xcd*(q+1) : r*(q+1) + (xcd - r)*q) + (orig >> 3);
  const int z   = wgid / grid_mn;
  const int rem = wgid - z*grid_mn;
  const int nb  = rem / grid_m;
  const int mb  = rem - nb*grid_m;
  const int m0 = mb*BM, n0 = nb*BN;
  const int tid = threadIdx.x, lane = tid & 63, wid = tid >> 6;

  if (EPI == 2 && n0 > m0 + (BM - 1)){            // fully-masked causal block
    float* C = (float*)Cb + (long)z * sC;
    constexpr int FIT = (BM*BN)/(THREADS*4);
    #pragma unroll
    for (int i = 0; i < FIT; i++){
      int idx4 = (tid + i*THREADS)*4;
      int rr = idx4 / BN, cc = idx4 - rr*BN;
      *(float4*)&C[(long)(m0+rr)*ldc + n0 + cc] = make_float4(-1e30f,-1e30f,-1e30f,-1e30f);
    }
    return;
  }

  const u16* A = Ab + (long)z*sA;
  const u16* B = Bb + (long)z*sB;

  // staging source addressing (inverse-swizzled columns; LDS dest linear)
  const int rS = tid >> 2;
  const int cS = (((tid & 3) ^ ((rS >> 1) & 3)) << 3);
  const u16* gA[AIT]; const u16* gB[BIT];
  #pragma unroll
  for (int i = 0; i < AIT; i++) gA[i] = A + (long)(m0 + rS + i*(THREADS/4))*lda + cS;
  #pragma unroll
  for (int i = 0; i < BIT; i++) gB[i] = B + (long)(n0 + rS + i*(THREADS/4))*ldb + cS;

  auto stage = [&](int kt, int buf){
    const int tb = buf*BUF;
    const int ko = kt << 5;
    #pragma unroll
    for (int i = 0; i < AIT; i++)
      gload16(gA[i] + ko, (void*)&S[tb + (i*THREADS + wid*64)*8]);
    #pragma unroll
    for (int i = 0; i < BIT; i++)
      gload16(gB[i] + ko, (void*)&S[tb + BM*32 + (i*THREADS + wid*64)*8]);
  };

  // fragment read offsets (swizzled)
  const int wr = wid / WN, wc = wid - wr*WN;
  const int fr = lane & 15, fk = lane >> 4;
  int aoff[MI], boff[NI];
  #pragma unroll
  for (int mi = 0; mi < MI; mi++){
    int rowm = wr*WMR + mi*16 + fr;
    aoff[mi] = rowm*32 + ((fk ^ ((rowm >> 1) & 3)) << 3);
  }
  #pragma unroll
  for (int ni = 0; ni < NI; ni++){
    int rown = wc*WNR + ni*16 + fr;
    boff[ni] = BM*32 + rown*32 + ((fk ^ ((rown >> 1) & 3)) << 3);
  }

  f32x4 acc[MI][NI] = {};

  stage(0,0); stage(1,1); stage(2,2);
  asm volatile("s_waitcnt vmcnt(8)" ::: "memory");
  __builtin_amdgcn_s_barrier();
  __builtin_amdgcn_sched_barrier(0);

  const int NT = K >> 5;
  for (int t = 0; t < NT; t++){
    int nx = t + 3; if (nx >= NT) nx -= NT;       // modular re-stage keeps vmcnt uniform
    stage(nx, (t+3)&3);
    const int tb = (t&3)*BUF;
    bf16x8 bfr[NI];
    #pragma unroll
    for (int ni = 0; ni < NI; ni++) bfr[ni] = *(const bf16x8*)&S[tb + boff[ni]];
    __builtin_amdgcn_s_setprio(1);
    #pragma unroll
    for (int mh = 0; mh < MI; mh += 4){
      bf16x8 afr[4];
      #pragma unroll
      for (int u = 0; u < 4; u++) afr[u] = *(const bf16x8*)&S[tb + aoff[mh+u]];
      #pragma unroll
      for (int u = 0; u < 4; u++)
        #pragma unroll
        for (int ni = 0; ni < NI; ni++)
          acc[mh+u][ni] = __builtin_amdgcn_mfma_f32_16x16x32_bf16(afr[u], bfr[ni], acc[mh+u][ni], 0, 0, 0);
    }
    __builtin_amdgcn_s_setprio(0);
    asm volatile("s_waitcnt vmcnt(8)" ::: "memory");   // tile t+1 landed; t+2,t+3 in flight
    __builtin_amdgcn_s_barrier();
    __builtin_amdgcn_sched_barrier(0);
  }

  // epilogue: D col = lane&15, row = (lane>>4)*4 + j
  const int er = (lane >> 4) * 4, ec = lane & 15;
  #pragma unroll
  for (int mi = 0; mi < MI; mi++){
    #pragma unroll
    for (int ni = 0; ni < NI; ni++){
      #pragma unroll
      for (int j = 0; j < 4; j++){
        int row = m0 + wr*WMR + mi*16 + er + j;
        int col = n0 + wc*WNR + ni*16 + ec;
        float v = acc[mi][ni][j];
        if (EPI == 0){
          ((float*)Cb + (long)z * sC)[(long)row * ldc + col] = v;
        } else if (EPI == 1){
          v = v > 0.f ? v : 0.f;
          ((u16*)Cb + (long)z * sC)[(long)row * ldc + col] = f2b(v);
        } else if (EPI == 2){
          v *= scale;
          if (col > row) v = -1e30f;
          ((float*)Cb + (long)z * sC)[(long)row * ldc + col] = v;
        } else {
          v = v > 0.f ? v : 0.f;
          float mfv = b2f((Mul + (long)z * sMul)[(long)row * ldmul + col]);
          ((u16*)Cb + (long)z * sC)[(long)row * ldc + col] = f2b(v * mfv);
        }
      }
    }
  }
  asm volatile("s_waitcnt vmcnt(0)" ::: "memory");  // drain stale re-stages before endpgm
}

// ---------- host ----------
extern "C" void kernel_launch(void* const* d_in, const int* in_sizes, int n_in,
                              void* d_out, int out_size, void* d_ws, size_t ws_size,
                              hipStream_t stream){
  (void)in_sizes; (void)n_in; (void)out_size; (void)ws_size;
  const int*   idx     = (const int*)  d_in[0];
  const float* embed   = (const float*)d_in[1];
  const float* encoder = (const float*)d_in[2];
  const float* encv    = (const float*)d_in[3];
  const float* decoder = (const float*)d_in[4];
  const float* lm_head = (const float*)d_in[5];
  const float* ln_w    = (const float*)d_in[6];
  const float* ln_b    = (const float*)d_in[7];
  float* out = (float*)d_out;

  char* p = (char*)d_ws;
  auto take = [&](size_t n){ char* r = p; p += (n + 255) & ~(size_t)255; return r; };
  u16*   encT  = (u16*)  take((size_t)NHH * ND * EE * 2);
  u16*   encvT = (u16*)  take((size_t)NHH * ND * EE * 2);
  u16*   decT  = (u16*)  take((size_t)EE * HNN * 2);
  u16*   lmhB  = (u16*)  take((size_t)VOC * EE * 2);
  float* xf    = (float*)take((size_t)TT * EE * 4);
  u16*   xb    = (u16*)  take((size_t)TT * EE * 2);
  u16*   xT    = (u16*)  take((size_t)EE * TT * 2);
  u16*   xs    = (u16*)  take((size_t)NHH * TT * ND * 2);
  char*  big   =         take((size_t)NHH * TT * TT * 4);
  u16*   attn  = (u16*)  take((size_t)NHH * TT * TT * 2);
  u16*   yb    = (u16*)  take((size_t)NHH * TT * EE * 2);
  float* part  = (float*)take((size_t)8 * TT * EE * 4);
  float* scores = (float*)big;
  float* yf     = (float*)big;
  u16*   xy     = (u16*)big;

  dim3 blk(256, 1, 1);

  transpose_f2b<<<dim3(ND / 32, EE / 32, NHH), blk, 0, stream>>>(encoder, (long)EE * ND, encT,  (long)ND * EE, EE, ND);
  transpose_f2b<<<dim3(ND / 32, EE / 32, NHH), blk, 0, stream>>>(encv,    (long)EE * ND, encvT, (long)ND * EE, EE, ND);
  transpose_f2b<<<dim3(EE / 32, HNN / 32, 1),  blk, 0, stream>>>(decoder, 0, decT, 0, HNN, EE);
  conv_f2b<<<dim3((VOC * EE) / 1024, 1, 1), blk, 0, stream>>>(lm_head, lmhB);

  embed_ln<<<dim3(TT, 1, 1), blk, 0, stream>>>(idx, embed, ln_w, ln_b, xf, xb, xT);

  const float scl = 0.022097086912079608f;  // 1/sqrt(2048)

  for (int L = 0; L < NLAYER; ++L){
    // x_sparse[h] = relu(x @ enc[h])  -> bf16 [H][T][N]
    gemm_pipe<256,256,2,4,1><<<dim3(4*8*NHH), dim3(512), 0, stream>>>(
        xb, 0, encT, (long)ND * EE, xs, (long)TT * ND,
        4, 32, EE, EE, EE, ND, 0.f, (const u16*)0, 0, 0);
    // scores[h] = causal(scale * xs[h] @ xs[h]^T) -> f32 [H][T][T]
    gemm_pipe<256,256,2,4,2><<<dim3(4*4*NHH), dim3(512), 0, stream>>>(
        xs, (long)TT * ND, xs, (long)TT * ND, scores, (long)TT * TT,
        4, 16, ND, ND, ND, TT, scl, (const u16*)0, 0, 0);
    softmax_rows<<<dim3(TT, NHH, 1), blk, 0, stream>>>(scores, attn);
    // y[h] = attn[h] @ x  -> f32 [H][T][E]
    gemm_pipe<128,128,2,2,0><<<dim3(8*6*NHH), dim3(256), 0, stream>>>(
        attn, (long)TT * TT, xT, 0, yf, (long)TT * EE,
        8, 48, TT, TT, TT, EE, 0.f, (const u16*)0, 0, 0);
    ln_rows<<<dim3(NHH * TT, 1, 1), blk, 0, stream>>>(yf, yb, ln_w, ln_b);
    // xy[t][h*N+n] = relu(y[h] @ encv[h]) * xs[h]  -> bf16 [T][H*N]
    gemm_pipe<256,256,2,4,3><<<dim3(4*8*NHH), dim3(512), 0, stream>>>(
        yb, (long)TT * EE, encvT, (long)ND * EE, xy, (long)ND,
        4, 32, EE, EE, EE, HNN, 0.f, xs, (long)TT * ND, ND);
    // y_mlp partials: split-K over 24576 (8 chunks of 3072)
    gemm_pipe<128,128,2,2,0><<<dim3(8*6*8), dim3(256), 0, stream>>>(
        xy, (long)3072, decT, (long)3072, part, (long)TT * EE,
        8, 48, 3072, HNN, HNN, EE, 0.f, (const u16*)0, 0, 0);
    residual_ln<<<dim3(TT, 1, 1), blk, 0, stream>>>(part, xf, xf, xb, xT, ln_w, ln_b);
  }

  // logits = x @ lm_head^T -> f32 [T][V]
  gemm_pipe<256,256,2,4,0><<<dim3(4*125), dim3(512), 0, stream>>>(
      xb, 0, lmhB, 0, out, 0,
      4, 500, EE, EE, EE, VOC, 0.f, (const u16*)0, 0, 0);
}